// Round 6
// baseline (28.012 us; speedup 1.0000x reference)
//
#include <hip/hip_runtime.h>
#include <hip/hip_bf16.h>

typedef float  f32x4  __attribute__((ext_vector_type(4)));
typedef short  bf16x8 __attribute__((ext_vector_type(8)));

#define NB   64
#define NL1  512
#define NL2  32
#define ND   600
#define NW   608     // padded K (zero tail 600..607)

static __device__ __forceinline__ short f2bf(float f) {
    __hip_bfloat16 h = __float2bfloat16(f);
    return __builtin_bit_cast(short, h);
}

// out[b,i,j] = ctx[b,i,:].w1 + asp[b,j,:].w2 + sum_d ctx[b,i,d]*w3[d]*asp[b,j,d]
//
// TLP design: 128-thread blocks (2 waves), each block owns a 16-row strip of
// one batch; the 2 waves split K (s=0..9 / 10..18) and combine via LDS.
// asp is NOT staged in LDS: per-XCD asp set = 614 KB, L2-resident (all of an
// XCD's blocks co-resident), B-fragments read direct from L2. w3 folds into
// the A-side; asp.w2 (aspterm) done by broadcast-A MFMAs on the idle matrix pipe.
__global__ __launch_bounds__(128, 4)
void align_kernel(const float* __restrict__ ctx,
                  const float* __restrict__ asp,
                  const float* __restrict__ wu,
                  float* __restrict__ out)
{
    __shared__ short w1bf[NW];        // bf16 w1 (acc2 broadcast B)
    __shared__ short w2bf[NW];        // bf16 w2 (acc3/acc4 broadcast A)
    __shared__ float w3s[NW];         // f32 w3 (A-side fold)
    __shared__ float comb[64][15];    // K-half combine (wave1 -> wave0)

    const int tid     = threadIdx.x;
    const int lane    = tid & 63;
    const int kh      = tid >> 6;     // K-half
    const int b       = blockIdx.x;   // id%8 = b%8 -> same-batch blocks same XCD
    const int rowbase = blockIdx.y * 16;

    const int r16 = lane & 15;        // A/B row (fragment), D col
    const int g   = lane >> 4;        // k-subgroup

    const float* actx = ctx + ((size_t)b * NL1 + rowbase + r16) * ND + 8 * g;
    const float* aspb = asp + ((size_t)b * NL2 + r16) * ND + 8 * g;  // j=r16; +16*ND for j=16+r16

    const int sbeg = kh ? 10 : 0;
    const int send = kh ? 19 : 10;

    // guarded 6-load issue for step t (t=18: lane-group g=3 is the zero tail)
#define ISSUE(t, C0, C1, A0, A1, B0, B1)                                   \
    if ((t) <= 17 || ((t) == 18 && g < 3)) {                               \
        C0 = *(const float4*)(actx + (t) * 32);                            \
        C1 = *(const float4*)(actx + (t) * 32 + 4);                        \
        A0 = *(const float4*)(aspb + (t) * 32);                            \
        A1 = *(const float4*)(aspb + (t) * 32 + 4);                        \
        B0 = *(const float4*)(aspb + 16 * ND + (t) * 32);                  \
        B1 = *(const float4*)(aspb + 16 * ND + (t) * 32 + 4);              \
    } else {                                                               \
        C0 = C1 = A0 = A1 = B0 = B1 = make_float4(0.f, 0.f, 0.f, 0.f);    \
    }

    // prologue loads issued before (and overlapping) the tiny w-staging
    float4 c0, c1, a0, a1, b0, b1;
    ISSUE(sbeg, c0, c1, a0, a1, b0, b1)

    for (int i = tid; i < NW; i += 128) {
        const bool v = i < ND;
        w1bf[i] = v ? f2bf(wu[i])        : (short)0;
        w2bf[i] = v ? f2bf(wu[ND + i])   : (short)0;
        w3s[i]  = v ? wu[2 * ND + i]     : 0.f;
    }
    __syncthreads();

    f32x4 acc0 = {0,0,0,0};   // cross, cols 0..15
    f32x4 acc1 = {0,0,0,0};   // cross, cols 16..31
    f32x4 acc2 = {0,0,0,0};   // ctx.w1  (B = w1 broadcast)
    f32x4 acc3 = {0,0,0,0};   // asp.w2, cols 0..15  (A = w2 broadcast)
    f32x4 acc4 = {0,0,0,0};   // asp.w2, cols 16..31

    #pragma unroll 1
    for (int s = sbeg; s < send; ++s) {
        float4 nc0, nc1, na0, na1, nb0, nb1;
        ISSUE(s + 1, nc0, nc1, na0, na1, nb0, nb1)   // t=19 -> zero branch

        const int k0g = s * 32 + 8 * g;
        const bf16x8 wf  = *(const bf16x8*)&w1bf[k0g];
        const bf16x8 w2f = *(const bf16x8*)&w2bf[k0g];
        const float4 w3a = *(const float4*)&w3s[k0g];
        const float4 w3b = *(const float4*)&w3s[k0g + 4];

        bf16x8 af, afw, f0, f1;
        af[0]  = f2bf(c0.x);        af[1]  = f2bf(c0.y);
        af[2]  = f2bf(c0.z);        af[3]  = f2bf(c0.w);
        af[4]  = f2bf(c1.x);        af[5]  = f2bf(c1.y);
        af[6]  = f2bf(c1.z);        af[7]  = f2bf(c1.w);
        afw[0] = f2bf(c0.x * w3a.x); afw[1] = f2bf(c0.y * w3a.y);
        afw[2] = f2bf(c0.z * w3a.z); afw[3] = f2bf(c0.w * w3a.w);
        afw[4] = f2bf(c1.x * w3b.x); afw[5] = f2bf(c1.y * w3b.y);
        afw[6] = f2bf(c1.z * w3b.z); afw[7] = f2bf(c1.w * w3b.w);
        f0[0] = f2bf(a0.x); f0[1] = f2bf(a0.y); f0[2] = f2bf(a0.z); f0[3] = f2bf(a0.w);
        f0[4] = f2bf(a1.x); f0[5] = f2bf(a1.y); f0[6] = f2bf(a1.z); f0[7] = f2bf(a1.w);
        f1[0] = f2bf(b0.x); f1[1] = f2bf(b0.y); f1[2] = f2bf(b0.z); f1[3] = f2bf(b0.w);
        f1[4] = f2bf(b1.x); f1[5] = f2bf(b1.y); f1[6] = f2bf(b1.z); f1[7] = f2bf(b1.w);

        acc0 = __builtin_amdgcn_mfma_f32_16x16x32_bf16(afw, f0, acc0, 0, 0, 0);
        acc1 = __builtin_amdgcn_mfma_f32_16x16x32_bf16(afw, f1, acc1, 0, 0, 0);
        acc2 = __builtin_amdgcn_mfma_f32_16x16x32_bf16(af,  wf, acc2, 0, 0, 0);
        acc3 = __builtin_amdgcn_mfma_f32_16x16x32_bf16(w2f, f0, acc3, 0, 0, 0);
        acc4 = __builtin_amdgcn_mfma_f32_16x16x32_bf16(w2f, f1, acc4, 0, 0, 0);

        c0 = nc0; c1 = nc1; a0 = na0; a1 = na1; b0 = nb0; b1 = nb1;
    }
#undef ISSUE

    // ---- K-half combine: wave1 -> LDS, wave0 adds + stores ----
    if (kh == 1) {
        float* c = comb[lane];
        c[0]  = acc0[0]; c[1]  = acc0[1]; c[2]  = acc0[2]; c[3]  = acc0[3];
        c[4]  = acc1[0]; c[5]  = acc1[1]; c[6]  = acc1[2]; c[7]  = acc1[3];
        c[8]  = acc2[0]; c[9]  = acc2[1]; c[10] = acc2[2]; c[11] = acc2[3];
        c[12] = acc3[0]; c[13] = acc4[0];
    }
    __syncthreads();
    if (kh == 0) {
        const float* c = comb[lane];
        const float atj0 = acc3[0] + c[12];
        const float atj1 = acc4[0] + c[13];
        float* orow = out + ((size_t)b * NL1 + rowbase + g * 4) * NL2;
        #pragma unroll
        for (int r = 0; r < 4; ++r) {
            const float ct = acc2[r] + c[8 + r];      // ctxterm[row g*4+r]
            orow[r * NL2 + r16]      = acc0[r] + c[r]     + ct + atj0;
            orow[r * NL2 + 16 + r16] = acc1[r] + c[4 + r] + ct + atj1;
        }
    }
}

extern "C" void kernel_launch(void* const* d_in, const int* in_sizes, int n_in,
                              void* d_out, int out_size, void* d_ws, size_t ws_size,
                              hipStream_t stream) {
    (void)in_sizes; (void)n_in; (void)d_ws; (void)ws_size; (void)out_size;
    // d_in: [0]=batch_size(int scalar), [1]=ctx f32, [2]=asp f32, [3]=w_u f32
    const float* ctx = (const float*)d_in[1];
    const float* asp = (const float*)d_in[2];
    const float* wu  = (const float*)d_in[3];
    float* out = (float*)d_out;
    dim3 grid(NB, NL1 / 16);
    align_kernel<<<grid, 128, 0, stream>>>(ctx, asp, wu, out);
}

// Round 7
// 21.647 us; speedup vs baseline: 1.2940x; 1.2940x over previous
//
#include <hip/hip_runtime.h>
#include <hip/hip_bf16.h>

typedef float  f32x4  __attribute__((ext_vector_type(4)));
typedef short  bf16x8 __attribute__((ext_vector_type(8)));
typedef short  s16x4  __attribute__((ext_vector_type(4)));

#define NB   64
#define NL1  512
#define NL2  32
#define ND   600
#define NDP  640      // asp LDS row stride in shorts: 80 chunks (mult of 8, XOR-closed)
#define NW1  608      // w1 padded to mult of 32
#define ROWS 64       // ctx rows per block (4 waves x 16)

static __device__ __forceinline__ short f2bf(float f) {
    __hip_bfloat16 h = __float2bfloat16(f);
    return __builtin_bit_cast(short, h);
}

// out[b,i,j] = ctx[b,i,:].w1 + asp[b,j,:].w2 + sum_d ctx[b,i,d]*w3[d]*asp[b,j,d]
__global__ __launch_bounds__(256, 2)
void align_kernel(const float* __restrict__ ctx,
                  const float* __restrict__ asp,
                  const float* __restrict__ wu,
                  float* __restrict__ out)
{
    __shared__ short aspw3[NL2 * NDP];     // 40 KB: bf16 asp*w3, 16B-chunk XOR swizzle
    __shared__ short w1bf[NW1];            // 1.2 KB: bf16 w1 (acc2 broadcast B)
    __shared__ float aspterm[NL2];
    __shared__ float ctxs[4][2][16][32];   // 16 KB: wave-private ctx slab double-buffer

    const int tid     = threadIdx.x;
    const int lane    = tid & 63;
    const int wid     = tid >> 6;
    const int b       = blockIdx.x;        // id%8 = b%8 -> same-batch blocks same XCD
    const int rowbase = blockIdx.y * ROWS;

    const int r16 = lane & 15;             // A row / D col
    const int g   = lane >> 4;             // k-subgroup
    const int jx  = lane & 7;
    const int r7  = r16 & 7;

    // staging lane map: instr q in {0,1} covers rows q*8+lr; lane reads 16B chunk lc.
    // Each load instr = 8 rows x 128B full-line windows (16 fully-used lines),
    // vs the old per-lane fragment scatter (32 half-used lines). This is the fix.
    const int lr = lane >> 3;              // 0..7
    const int lc = lane & 7;               // chunk within 128B window
    const float* ctx_base = ctx + ((size_t)b * NL1 + rowbase + wid * 16) * ND;

    // load slab t (window floats [t*32, t*32+32) of the wave's 16 rows) into regs.
    // t==18: chunks 6,7 are k=600..607 -> zero (w1bf/aspw3 tails are also zero).
#define LOADSLAB(t, A0, A1) do {                                               \
        if ((t) <= 18) {                                                       \
            if ((t) == 18 && lc >= 6) {                                        \
                A0 = (f32x4){0.f,0.f,0.f,0.f};                                 \
                A1 = (f32x4){0.f,0.f,0.f,0.f};                                 \
            } else {                                                           \
                A0 = *(const f32x4*)(ctx_base + (size_t)lr * ND     + (t)*32 + lc*4); \
                A1 = *(const f32x4*)(ctx_base + (size_t)(8+lr) * ND + (t)*32 + lc*4); \
            }                                                                  \
        }                                                                      \
    } while (0)

    // write slab t regs into buf[t&1], XOR-swizzled chunk slot (2-way read = free)
#define WRITESLAB(t, A0, A1) do {                                              \
        if ((t) <= 18) {                                                       \
            *(f32x4*)&ctxs[wid][(t)&1][lr]  [(lc ^ lr) * 4] = A0;              \
            *(f32x4*)&ctxs[wid][(t)&1][8+lr][(lc ^ lr) * 4] = A1;              \
        }                                                                      \
    } while (0)

    // 3-slot static rotation: iter s = {load s+3, read s, write s+1}
    f32x4 P0a, P0b, P1a, P1b, P2a, P2b;
    LOADSLAB(0, P0a, P0b);
    LOADSLAB(1, P1a, P1b);
    LOADSLAB(2, P2a, P2b);

    // ---- stage w1 as bf16 (zero-padded to 608) ----
    for (int i = tid; i < NW1; i += 256)
        w1bf[i] = (i < ND) ? f2bf(wu[i]) : (short)0;

    // ---- stage asp*w3 (bf16, swizzled) + asp_term (R5 verbatim) ----
    {
        const int j   = tid >> 3;    // asp row 0..31
        const int e   = tid & 7;
        const int jxs = j & 7;

        aspw3[j * NDP + ((75 ^ jxs) << 3) + e] = 0;   // zero-pad k=600..607

        const int sub = tid & 7;
        const float* arow = asp + ((size_t)b * NL2 + j) * ND;
        float at = 0.f;
        #pragma unroll
        for (int m = 0; m < 19; ++m) {
            const int k = m * 32 + sub * 4;
            if (k < ND) {
                const float4 v  = *(const float4*)(arow + k);
                const float4 w2 = *(const float4*)(wu + ND + k);
                const float4 w3 = *(const float4*)(wu + 2 * ND + k);
                at += v.x * w2.x + v.y * w2.y + v.z * w2.z + v.w * w2.w;
                s16x4 h;
                h.x = f2bf(v.x * w3.x);
                h.y = f2bf(v.y * w3.y);
                h.z = f2bf(v.z * w3.z);
                h.w = f2bf(v.w * w3.w);
                const int c = (k >> 3) ^ jxs;
                *(s16x4*)&aspw3[j * NDP + (c << 3) + (k & 7)] = h;
            }
        }
        at += __shfl_xor(at, 1);
        at += __shfl_xor(at, 2);
        at += __shfl_xor(at, 4);
        if (sub == 0) aspterm[j] = at;
    }

    WRITESLAB(0, P0a, P0b);      // slab 0 into buf0 (same-wave ds ordering)
    __syncthreads();

    f32x4 acc0 = {0,0,0,0};      // cross, cols 0..15
    f32x4 acc1 = {0,0,0,0};      // cross, cols 16..31
    f32x4 acc2 = {0,0,0,0};      // ctx.w1 (B = w1 broadcast)

#define STEP(s, LA0, LA1, WA0, WA1) do {                                       \
        LOADSLAB((s)+3, LA0, LA1);                                             \
        const f32x4 fa = *(const f32x4*)&ctxs[wid][(s)&1][r16][((2*g    ) ^ r7) * 4]; \
        const f32x4 fb = *(const f32x4*)&ctxs[wid][(s)&1][r16][((2*g + 1) ^ r7) * 4]; \
        bf16x8 af;                                                             \
        af[0] = f2bf(fa.x); af[1] = f2bf(fa.y); af[2] = f2bf(fa.z); af[3] = f2bf(fa.w); \
        af[4] = f2bf(fb.x); af[5] = f2bf(fb.y); af[6] = f2bf(fb.z); af[7] = f2bf(fb.w); \
        const int cB = (((s) * 4 + g) ^ jx) << 3;                              \
        const bf16x8 f0 = *(const bf16x8*)&aspw3[r16 * NDP + cB];              \
        const bf16x8 f1 = *(const bf16x8*)&aspw3[(16 + r16) * NDP + cB];       \
        const bf16x8 wf = *(const bf16x8*)&w1bf[(s) * 32 + 8 * g];             \
        acc0 = __builtin_amdgcn_mfma_f32_16x16x32_bf16(af, f0, acc0, 0, 0, 0); \
        acc1 = __builtin_amdgcn_mfma_f32_16x16x32_bf16(af, f1, acc1, 0, 0, 0); \
        acc2 = __builtin_amdgcn_mfma_f32_16x16x32_bf16(af, wf, acc2, 0, 0, 0); \
        WRITESLAB((s)+1, WA0, WA1);                                            \
    } while (0)

    #pragma unroll 1
    for (int m = 0; m < 18; m += 6) {    // s = 0..17
        STEP(m + 0, P0a, P0b, P1a, P1b);
        STEP(m + 1, P1a, P1b, P2a, P2b);
        STEP(m + 2, P2a, P2b, P0a, P0b);
        STEP(m + 3, P0a, P0b, P1a, P1b);
        STEP(m + 4, P1a, P1b, P2a, P2b);
        STEP(m + 5, P2a, P2b, P0a, P0b);
    }
    STEP(18, P0a, P0b, P1a, P1b);        // peeled: load/write guards drop out

#undef STEP
#undef WRITESLAB
#undef LOADSLAB

    // ---- epilogue: D row = g*4 + reg, D col = r16 (verified C/D map, m89) ----
    const float atj0 = aspterm[r16];
    const float atj1 = aspterm[16 + r16];
    float* orow = out + ((size_t)b * NL1 + rowbase + wid * 16 + g * 4) * NL2;
    #pragma unroll
    for (int r = 0; r < 4; ++r) {
        const float cterm = acc2[r];
        orow[r * NL2 + r16]      = acc0[r] + cterm + atj0;
        orow[r * NL2 + 16 + r16] = acc1[r] + cterm + atj1;
    }
}

extern "C" void kernel_launch(void* const* d_in, const int* in_sizes, int n_in,
                              void* d_out, int out_size, void* d_ws, size_t ws_size,
                              hipStream_t stream) {
    (void)in_sizes; (void)n_in; (void)d_ws; (void)ws_size; (void)out_size;
    // d_in: [0]=batch_size(int scalar), [1]=ctx f32, [2]=asp f32, [3]=w_u f32
    const float* ctx = (const float*)d_in[1];
    const float* asp = (const float*)d_in[2];
    const float* wu  = (const float*)d_in[3];
    float* out = (float*)d_out;
    dim3 grid(NB, NL1 / ROWS);
    align_kernel<<<grid, 256, 0, stream>>>(ctx, asp, wu, out);
}